// Round 1
// baseline (3998.661 us; speedup 1.0000x reference)
//
#include <hip/hip_runtime.h>
#include <hip/hip_bf16.h>

typedef __hip_bfloat16 bf16;
typedef __bf16 bf16x8_t __attribute__((ext_vector_type(8)));
typedef float f32x4_t __attribute__((ext_vector_type(4)));

#define HID 3584
#define SEQ 2048
#define NBATCH 2
#define MTOK 4096
#define NHEADS 16
#define NKVH 8
#define HDIM 256
#define QOUT 4096
#define KOUT 2048
#define INTERD 14336
#define EPSF 1e-6f

static __device__ __forceinline__ unsigned short f2bu(float f) {
  union { bf16 b; unsigned short u; } cv;
  cv.b = __float2bfloat16(f);
  return cv.u;
}

static __device__ __forceinline__ f32x4_t mfma16(bf16x8_t a, bf16x8_t b, f32x4_t c) {
  return __builtin_amdgcn_mfma_f32_16x16x32_bf16(a, b, c, 0, 0, 0);
}

static __device__ __forceinline__ void gl_lds16(const void* g, void* l) {
  __builtin_amdgcn_global_load_lds((__attribute__((address_space(1))) void*)g,
                                   (__attribute__((address_space(3))) void*)l,
                                   16, 0, 0);
}

static __device__ __forceinline__ float block_reduce_sum(float v) {
  __shared__ float buf[4];
  #pragma unroll
  for (int m = 1; m < 64; m <<= 1) v += __shfl_xor(v, m, 64);
  __syncthreads();
  if ((threadIdx.x & 63) == 0) buf[threadIdx.x >> 6] = v;
  __syncthreads();
  return buf[0] + buf[1] + buf[2] + buf[3];
}

// ---------------------------------------------------------------------------
// GEMM: C[M][N] = A[M][K](bf16) * B[N][K](f32, converted to bf16 on the fly)^T
// 128x128 tile, BK=32, 4 waves each computing 64x64 via 4x4 MFMA 16x16x32.
// ---------------------------------------------------------------------------
enum { EPI_BF16 = 0, EPI_F32 = 1, EPI_VT = 2, EPI_GELUMUL = 3 };

template <int EPI>
__global__ __launch_bounds__(256) void gemm_bt(
    const bf16* __restrict__ A, const float* __restrict__ Bw,
    void* __restrict__ Cout, const bf16* __restrict__ aux,
    int Mdim, int Ndim, int Kdim) {
  __shared__ __align__(16) bf16 As[128 * 32];
  __shared__ __align__(16) bf16 Bs[128 * 32];

  const int n0 = blockIdx.x * 128;
  const int m0 = blockIdx.y * 128;
  const int t = threadIdx.x;
  const int w = t >> 6, l = t & 63;
  const int wr = w >> 1, wc = w & 1;
  const int lr = l & 15, lg = l >> 4, lk = lg * 8;

  f32x4_t acc[4][4];
  #pragma unroll
  for (int i = 0; i < 4; i++)
    #pragma unroll
    for (int j = 0; j < 4; j++) acc[i][j] = (f32x4_t){0.f, 0.f, 0.f, 0.f};

  // A staging geometry: lds byte offset o = i*4096 + w*1024 + l*16
  const int oA = w * 1024 + l * 16;
  const int rA0 = oA >> 6;            // rows 0..63
  const int cA0 = (oA & 63) >> 1;     // element col within BK
  const bf16* Ab0 = A + (size_t)(m0 + rA0) * Kdim + cA0;
  const bf16* Ab1 = A + (size_t)(m0 + rA0 + 64) * Kdim + cA0;

  // B staging geometry: thread t -> weight row rB = t>>1, f32 cols cB..cB+15
  const int rB = t >> 1, cB = (t & 1) * 16;
  const float* Bb = Bw + (size_t)(n0 + rB) * Kdim + cB;

  for (int kt = 0; kt < Kdim; kt += 32) {
    __syncthreads();  // previous fragment reads done before overwrite
    gl_lds16(Ab0 + kt, (char*)As + w * 1024);
    gl_lds16(Ab1 + kt, (char*)As + 4096 + w * 1024);
    {
      const float4* src = (const float4*)(Bb + kt);
      char* dstb = (char*)Bs + rB * 64 + cB * 2;
      #pragma unroll
      for (int j = 0; j < 4; j++) {
        float4 f = src[j];
        ushort4 hv;
        hv.x = f2bu(f.x); hv.y = f2bu(f.y); hv.z = f2bu(f.z); hv.w = f2bu(f.w);
        *(ushort4*)(dstb + j * 8) = hv;
      }
    }
    __syncthreads();  // waits vmcnt(0) (global_load_lds) + lgkmcnt(0)

    bf16x8_t af[4], bfr[4];
    #pragma unroll
    for (int i = 0; i < 4; i++) {
      af[i]  = *(const bf16x8_t*)(As + (wr * 64 + i * 16 + lr) * 32 + lk);
      bfr[i] = *(const bf16x8_t*)(Bs + (wc * 64 + i * 16 + lr) * 32 + lk);
    }
    #pragma unroll
    for (int mi = 0; mi < 4; mi++)
      #pragma unroll
      for (int ni = 0; ni < 4; ni++)
        acc[mi][ni] = mfma16(af[mi], bfr[ni], acc[mi][ni]);
  }

  // Epilogue. C/D layout: col = lane&15, row = (lane>>4)*4 + reg.
  const int row0 = m0 + wr * 64 + lg * 4;
  const int col0 = n0 + wc * 64 + lr;
  #pragma unroll
  for (int mi = 0; mi < 4; mi++) {
    #pragma unroll
    for (int ni = 0; ni < 4; ni++) {
      #pragma unroll
      for (int r = 0; r < 4; r++) {
        const int row = row0 + mi * 16 + r;
        const int col = col0 + ni * 16;
        const float v = acc[mi][ni][r];
        if constexpr (EPI == EPI_BF16) {
          ((bf16*)Cout)[(size_t)row * Ndim + col] = __float2bfloat16(v);
        } else if constexpr (EPI == EPI_F32) {
          ((float*)Cout)[(size_t)row * Ndim + col] = v;
        } else if constexpr (EPI == EPI_VT) {
          // write V transposed: vt[(b*8+kvh)][d][s], s = row%SEQ
          const int kvh = col >> 8, d = col & 255;
          const int bb = row >> 11, s = row & 2047;
          ((bf16*)Cout)[(((size_t)((bb * 8 + kvh) * 256 + d)) << 11) + s] =
              __float2bfloat16(v);
        } else {  // EPI_GELUMUL: out = gelu_tanh(aux) * acc, in-place over aux ok
          const float g = __bfloat162float(aux[(size_t)row * Ndim + col]);
          const float u = 0.7978845608028654f * (g + 0.044715f * g * g * g);
          const float gl = 0.5f * g * (1.f + tanhf(u));
          ((bf16*)Cout)[(size_t)row * Ndim + col] = __float2bfloat16(gl * v);
        }
      }
    }
  }
  (void)aux;
  (void)Mdim;
}

// ---------------------------------------------------------------------------
// RMSNorm of input hidden -> bf16
// ---------------------------------------------------------------------------
__global__ __launch_bounds__(256) void rmsnorm_in(
    const float* __restrict__ x, const float* __restrict__ w,
    bf16* __restrict__ out) {
  const int row = blockIdx.x, t = threadIdx.x;
  const float4* xr = (const float4*)(x + (size_t)row * HID);
  float4 v[4];
  float ss = 0.f;
  #pragma unroll
  for (int j = 0; j < 4; j++) {
    const int idx = t + 256 * j;
    if (idx < HID / 4) {
      v[j] = xr[idx];
      ss += v[j].x * v[j].x + v[j].y * v[j].y + v[j].z * v[j].z + v[j].w * v[j].w;
    }
  }
  ss = block_reduce_sum(ss);
  const float sc = rsqrtf(ss * (1.f / HID) + EPSF);
  const float4* w4 = (const float4*)w;
  bf16* orow = out + (size_t)row * HID;
  #pragma unroll
  for (int j = 0; j < 4; j++) {
    const int idx = t + 256 * j;
    if (idx < HID / 4) {
      const float4 wv = w4[idx];
      ushort4 o;
      o.x = f2bu(v[j].x * sc * (1.f + wv.x));
      o.y = f2bu(v[j].y * sc * (1.f + wv.y));
      o.z = f2bu(v[j].z * sc * (1.f + wv.z));
      o.w = f2bu(v[j].w * sc * (1.f + wv.w));
      *(ushort4*)(orow + idx * 4) = o;
    }
  }
}

// ---------------------------------------------------------------------------
// RoPE in-place on q (16 heads) and k (8 heads), bf16.
// grid (MTOK, 24), block 128 = one (token, head)
// ---------------------------------------------------------------------------
__global__ __launch_bounds__(128) void rope_kernel(
    bf16* __restrict__ q, bf16* __restrict__ k,
    const float* __restrict__ cosb, const float* __restrict__ sinb) {
  const int tok = blockIdx.x;
  const int hs = blockIdx.y;
  const int d = threadIdx.x;  // 0..127
  const int s = tok & (SEQ - 1);
  bf16* ptr = (hs < NHEADS)
                  ? q + (size_t)tok * QOUT + hs * HDIM
                  : k + (size_t)tok * KOUT + (hs - NHEADS) * HDIM;
  const float c = cosb[s * HDIM + d];
  const float sn = sinb[s * HDIM + d];
  const float x0 = __bfloat162float(ptr[d]);
  const float x1 = __bfloat162float(ptr[d + 128]);
  ptr[d] = __float2bfloat16(x0 * c - x1 * sn);
  ptr[d + 128] = __float2bfloat16(x1 * c + x0 * sn);
}

// ---------------------------------------------------------------------------
// Flash attention, sliding window 1024, softcap 50, fixed-base softmax.
// grid (SEQ/64, NHEADS, NBATCH), 4 waves; each wave owns 16 q-rows.
// ---------------------------------------------------------------------------
__global__ __launch_bounds__(256) void attn_kernel(
    const bf16* __restrict__ q, const bf16* __restrict__ k,
    const bf16* __restrict__ vt, bf16* __restrict__ out) {
  __shared__ __align__(16) bf16 plds[4][16 * 32];

  const int qt = blockIdx.x, h = blockIdx.y, b = blockIdx.z;
  const int w = threadIdx.x >> 6, l = threadIdx.x & 63;
  const int kvh = h >> 1;
  const int qbase = qt * 64 + w * 16;  // within sequence
  const int lr = l & 15, lg = l >> 4, lk = lg * 8;

  // Q fragments (A-operand): rows qbase+lr, d chunks of 32
  bf16x8_t qf[8];
  const bf16* qrow = q + (size_t)(b * SEQ + qbase + lr) * QOUT + h * HDIM;
  #pragma unroll
  for (int c = 0; c < 8; c++) qf[c] = *(const bf16x8_t*)(qrow + c * 32 + lk);

  f32x4_t acc[16];
  #pragma unroll
  for (int i = 0; i < 16; i++) acc[i] = (f32x4_t){0.f, 0.f, 0.f, 0.f};
  float L[4] = {0.f, 0.f, 0.f, 0.f};

  const bf16* kp = k + (size_t)(b * SEQ) * KOUT + kvh * HDIM;
  const bf16* vp = vt + (size_t)(b * NKVH + kvh) * HDIM * SEQ;
  bf16* pl = &plds[w][0];

  int kstart = qbase - 1023;
  if (kstart < 0) kstart = 0;
  kstart &= ~31;
  const int kend = qbase + 15;

  for (int kb = kstart; kb <= kend; kb += 32) {
    // QK^T: two 16-key column subtiles
    f32x4_t s0 = (f32x4_t){0.f, 0.f, 0.f, 0.f};
    f32x4_t s1 = (f32x4_t){0.f, 0.f, 0.f, 0.f};
    #pragma unroll
    for (int c = 0; c < 8; c++) {
      bf16x8_t k0 = *(const bf16x8_t*)(kp + (size_t)(kb + lr) * KOUT + c * 32 + lk);
      bf16x8_t k1 = *(const bf16x8_t*)(kp + (size_t)(kb + 16 + lr) * KOUT + c * 32 + lk);
      s0 = mfma16(qf[c], k0, s0);
      s1 = mfma16(qf[c], k1, s1);
    }
    // softmax (fixed base: softcap bounds scores to (-50,50))
    float p[8];
    #pragma unroll
    for (int sub = 0; sub < 2; sub++) {
      const int j = kb + sub * 16 + lr;
      #pragma unroll
      for (int r = 0; r < 4; r++) {
        const int i = qbase + lg * 4 + r;
        float sc = (sub ? s1[r] : s0[r]) * 0.0625f;
        sc = 50.f * tanhf(sc * 0.02f);
        const bool ok = (j <= i) && (j > i - 1024);
        p[sub * 4 + r] = ok ? __expf(sc) : 0.f;
      }
    }
    #pragma unroll
    for (int r = 0; r < 4; r++) {
      float ps = p[r] + p[4 + r];
      ps += __shfl_xor(ps, 1, 64);
      ps += __shfl_xor(ps, 2, 64);
      ps += __shfl_xor(ps, 4, 64);
      ps += __shfl_xor(ps, 8, 64);
      L[r] += ps;
    }
    // P -> LDS (wave-private) -> A-fragment for PV
    #pragma unroll
    for (int sub = 0; sub < 2; sub++)
      #pragma unroll
      for (int r = 0; r < 4; r++)
        pl[(lg * 4 + r) * 32 + sub * 16 + lr] = __float2bfloat16(p[sub * 4 + r]);
    asm volatile("s_waitcnt lgkmcnt(0)" ::: "memory");
    const bf16x8_t pa = *(const bf16x8_t*)(pl + lr * 32 + lk);
    #pragma unroll
    for (int dt = 0; dt < 16; dt++) {
      bf16x8_t bv = *(const bf16x8_t*)(vp + (size_t)(dt * 16 + lr) * SEQ + kb + lk);
      acc[dt] = mfma16(pa, bv, acc[dt]);
    }
  }

  float rL[4];
  #pragma unroll
  for (int r = 0; r < 4; r++) rL[r] = 1.f / L[r];
  #pragma unroll
  for (int dt = 0; dt < 16; dt++) {
    #pragma unroll
    for (int r = 0; r < 4; r++) {
      const int tok = b * SEQ + qbase + lg * 4 + r;
      out[(size_t)tok * QOUT + h * HDIM + dt * 16 + lr] =
          __float2bfloat16(acc[dt][r] * rL[r]);
    }
  }
}

// ---------------------------------------------------------------------------
// fuse1: h1 = hidden + rmsnorm(attn_proj, w_post); y = bf16(rmsnorm(h1, w_pre))
// ---------------------------------------------------------------------------
__global__ __launch_bounds__(256) void fuse_attn(
    const float* __restrict__ hidden, const float* __restrict__ ap,
    const float* __restrict__ w_post, const float* __restrict__ w_pre,
    float* __restrict__ h1, bf16* __restrict__ y) {
  const int row = blockIdx.x, t = threadIdx.x;
  const float4* ar = (const float4*)(ap + (size_t)row * HID);
  const float4* hr = (const float4*)(hidden + (size_t)row * HID);
  float4 a[4];
  float ss = 0.f;
  #pragma unroll
  for (int j = 0; j < 4; j++) {
    const int idx = t + 256 * j;
    if (idx < HID / 4) {
      a[j] = ar[idx];
      ss += a[j].x * a[j].x + a[j].y * a[j].y + a[j].z * a[j].z + a[j].w * a[j].w;
    }
  }
  ss = block_reduce_sum(ss);
  const float sc = rsqrtf(ss * (1.f / HID) + EPSF);
  const float4* wpo = (const float4*)w_post;
  float4* h1r = (float4*)(h1 + (size_t)row * HID);
  float4 hv[4];
  float ss2 = 0.f;
  #pragma unroll
  for (int j = 0; j < 4; j++) {
    const int idx = t + 256 * j;
    if (idx < HID / 4) {
      const float4 wv = wpo[idx];
      const float4 x = hr[idx];
      hv[j].x = x.x + a[j].x * sc * (1.f + wv.x);
      hv[j].y = x.y + a[j].y * sc * (1.f + wv.y);
      hv[j].z = x.z + a[j].z * sc * (1.f + wv.z);
      hv[j].w = x.w + a[j].w * sc * (1.f + wv.w);
      ss2 += hv[j].x * hv[j].x + hv[j].y * hv[j].y + hv[j].z * hv[j].z + hv[j].w * hv[j].w;
      h1r[idx] = hv[j];
    }
  }
  ss2 = block_reduce_sum(ss2);
  const float sc2 = rsqrtf(ss2 * (1.f / HID) + EPSF);
  const float4* wpr = (const float4*)w_pre;
  bf16* yr = y + (size_t)row * HID;
  #pragma unroll
  for (int j = 0; j < 4; j++) {
    const int idx = t + 256 * j;
    if (idx < HID / 4) {
      const float4 wv = wpr[idx];
      ushort4 o;
      o.x = f2bu(hv[j].x * sc2 * (1.f + wv.x));
      o.y = f2bu(hv[j].y * sc2 * (1.f + wv.y));
      o.z = f2bu(hv[j].z * sc2 * (1.f + wv.z));
      o.w = f2bu(hv[j].w * sc2 * (1.f + wv.w));
      *(ushort4*)(yr + idx * 4) = o;
    }
  }
}

// ---------------------------------------------------------------------------
// fuse2: out = h1 + rmsnorm(mlp, w_post_ff)
// ---------------------------------------------------------------------------
__global__ __launch_bounds__(256) void fuse_out(
    const float* __restrict__ h1, const float* __restrict__ mlp,
    const float* __restrict__ w, float* __restrict__ out) {
  const int row = blockIdx.x, t = threadIdx.x;
  const float4* mr = (const float4*)(mlp + (size_t)row * HID);
  float4 m[4];
  float ss = 0.f;
  #pragma unroll
  for (int j = 0; j < 4; j++) {
    const int idx = t + 256 * j;
    if (idx < HID / 4) {
      m[j] = mr[idx];
      ss += m[j].x * m[j].x + m[j].y * m[j].y + m[j].z * m[j].z + m[j].w * m[j].w;
    }
  }
  ss = block_reduce_sum(ss);
  const float sc = rsqrtf(ss * (1.f / HID) + EPSF);
  const float4* hr = (const float4*)(h1 + (size_t)row * HID);
  const float4* w4 = (const float4*)w;
  float4* orow = (float4*)(out + (size_t)row * HID);
  #pragma unroll
  for (int j = 0; j < 4; j++) {
    const int idx = t + 256 * j;
    if (idx < HID / 4) {
      const float4 wv = w4[idx];
      const float4 x = hr[idx];
      float4 o;
      o.x = x.x + m[j].x * sc * (1.f + wv.x);
      o.y = x.y + m[j].y * sc * (1.f + wv.y);
      o.z = x.z + m[j].z * sc * (1.f + wv.z);
      o.w = x.w + m[j].w * sc * (1.f + wv.w);
      orow[idx] = o;
    }
  }
}

// ---------------------------------------------------------------------------
extern "C" void kernel_launch(void* const* d_in, const int* in_sizes, int n_in,
                              void* d_out, int out_size, void* d_ws,
                              size_t ws_size, hipStream_t stream) {
  const float* hidden = (const float*)d_in[0];
  const float* cosb = (const float*)d_in[1];
  const float* sinb = (const float*)d_in[2];
  const float* Wq = (const float*)d_in[3];
  const float* Wk = (const float*)d_in[4];
  const float* Wv = (const float*)d_in[5];
  const float* Wo = (const float*)d_in[6];
  const float* Wgate = (const float*)d_in[7];
  const float* Wup = (const float*)d_in[8];
  const float* Wdown = (const float*)d_in[9];
  const float* w_in = (const float*)d_in[10];
  const float* w_post_attn = (const float*)d_in[11];
  const float* w_pre_ff = (const float*)d_in[12];
  const float* w_post_ff = (const float*)d_in[13];
  float* out = (float*)d_out;

  char* ws = (char*)d_ws;
  // Region 0 (63 MB): xn + q, later overlaid by attn_proj, then mlp
  bf16* xn = (bf16*)(ws);                                 // 29,360,128 B
  bf16* q = (bf16*)(ws + 29360128);                       // 33,554,432 B
  float* attn_proj = (float*)(ws);                        // 58,720,256 B (after q dead)
  float* mlp = (float*)(ws);                              // 58,720,256 B (after attn_proj dead)
  // Region 1 (67 MB): k + vt + attn_out, later overlaid by h1
  bf16* kbuf = (bf16*)(ws + 62914560);                    // 16,777,216 B
  bf16* vt = (bf16*)(ws + 62914560 + 16777216);           // 16,777,216 B
  bf16* attn_out = (bf16*)(ws + 62914560 + 33554432);     // 33,554,432 B
  float* h1 = (float*)(ws + 62914560);                    // 58,720,256 B (after attn dead)
  // Region 2: y
  bf16* y = (bf16*)(ws + 130023424);                      // 29,360,128 B
  // Region 3: gate (gu written in-place)
  bf16* gate = (bf16*)(ws + 159383552);                   // 117,440,512 B
  // Total: 276,824,064 B

  (void)in_sizes; (void)n_in; (void)out_size; (void)ws_size;

  rmsnorm_in<<<MTOK, 256, 0, stream>>>(hidden, w_in, xn);
  gemm_bt<EPI_BF16><<<dim3(QOUT / 128, MTOK / 128), 256, 0, stream>>>(
      xn, Wq, q, nullptr, MTOK, QOUT, HID);
  gemm_bt<EPI_BF16><<<dim3(KOUT / 128, MTOK / 128), 256, 0, stream>>>(
      xn, Wk, kbuf, nullptr, MTOK, KOUT, HID);
  gemm_bt<EPI_VT><<<dim3(KOUT / 128, MTOK / 128), 256, 0, stream>>>(
      xn, Wv, vt, nullptr, MTOK, KOUT, HID);
  rope_kernel<<<dim3(MTOK, NHEADS + NKVH), 128, 0, stream>>>(q, kbuf, cosb, sinb);
  attn_kernel<<<dim3(SEQ / 64, NHEADS, NBATCH), 256, 0, stream>>>(
      q, kbuf, vt, attn_out);
  gemm_bt<EPI_F32><<<dim3(HID / 128, MTOK / 128), 256, 0, stream>>>(
      attn_out, Wo, attn_proj, nullptr, MTOK, HID, QOUT);
  fuse_attn<<<MTOK, 256, 0, stream>>>(hidden, attn_proj, w_post_attn, w_pre_ff,
                                      h1, y);
  gemm_bt<EPI_BF16><<<dim3(INTERD / 128, MTOK / 128), 256, 0, stream>>>(
      y, Wgate, gate, nullptr, MTOK, INTERD, HID);
  gemm_bt<EPI_GELUMUL><<<dim3(INTERD / 128, MTOK / 128), 256, 0, stream>>>(
      y, Wup, gate, gate, MTOK, INTERD, HID);
  gemm_bt<EPI_F32><<<dim3(HID / 128, MTOK / 128), 256, 0, stream>>>(
      gate, Wdown, mlp, nullptr, MTOK, HID, INTERD);
  fuse_out<<<MTOK, 256, 0, stream>>>(h1, mlp, w_post_ff, out);
}

// Round 2
// 3330.461 us; speedup vs baseline: 1.2006x; 1.2006x over previous
//
#include <hip/hip_runtime.h>
#include <hip/hip_bf16.h>

typedef __hip_bfloat16 bf16;
typedef __bf16 bf16x8_t __attribute__((ext_vector_type(8)));
typedef float f32x4_t __attribute__((ext_vector_type(4)));
typedef unsigned short u16x8_t __attribute__((ext_vector_type(8)));

#define HID 3584
#define SEQ 2048
#define NBATCH 2
#define MTOK 4096
#define NHEADS 16
#define NKVH 8
#define HDIM 256
#define QOUT 4096
#define KOUT 2048
#define INTERD 14336
#define EPSF 1e-6f

static __device__ __forceinline__ unsigned short f2bu(float f) {
  union { bf16 b; unsigned short u; } cv;
  cv.b = __float2bfloat16(f);
  return cv.u;
}

static __device__ __forceinline__ f32x4_t mfma16(bf16x8_t a, bf16x8_t b, f32x4_t c) {
  return __builtin_amdgcn_mfma_f32_16x16x32_bf16(a, b, c, 0, 0, 0);
}

static __device__ __forceinline__ void gl_lds16(const void* g, void* l) {
  __builtin_amdgcn_global_load_lds((__attribute__((address_space(1))) void*)g,
                                   (__attribute__((address_space(3))) void*)l,
                                   16, 0, 0);
}

static __device__ __forceinline__ float block_reduce_sum(float v) {
  __shared__ float buf[4];
  #pragma unroll
  for (int m = 1; m < 64; m <<= 1) v += __shfl_xor(v, m, 64);
  __syncthreads();
  if ((threadIdx.x & 63) == 0) buf[threadIdx.x >> 6] = v;
  __syncthreads();
  return buf[0] + buf[1] + buf[2] + buf[3];
}

// ---------------------------------------------------------------------------
// weight convert: f32 -> bf16, 8 elems/thread, grid-stride
// ---------------------------------------------------------------------------
__global__ __launch_bounds__(256) void cvt_w(
    const float* __restrict__ src, bf16* __restrict__ dst, int n) {
  const int stride = gridDim.x * 256 * 8;
  for (int i = (blockIdx.x * 256 + threadIdx.x) * 8; i < n; i += stride) {
    const float4 a = *(const float4*)(src + i);
    const float4 b = *(const float4*)(src + i + 4);
    u16x8_t o;
    o[0] = f2bu(a.x); o[1] = f2bu(a.y); o[2] = f2bu(a.z); o[3] = f2bu(a.w);
    o[4] = f2bu(b.x); o[5] = f2bu(b.y); o[6] = f2bu(b.z); o[7] = f2bu(b.w);
    *(u16x8_t*)(dst + i) = o;
  }
}

// ---------------------------------------------------------------------------
// GEMM: C[M][N] = A[M][K](bf16) * B[N][K]^T
// BBF16=true : B is bf16, staged via global_load_lds (m97 structure)
// BBF16=false: B is f32, converted through VALU (fallback, ws-limited)
// 128x128 tile, BK=32, 4 waves each computing 64x64 via 4x4 MFMA 16x16x32.
// ---------------------------------------------------------------------------
enum { EPI_BF16 = 0, EPI_F32 = 1, EPI_VT = 2, EPI_GELUMUL = 3 };

template <int EPI, bool BBF16>
__global__ __launch_bounds__(256) void gemm_bt(
    const bf16* __restrict__ A, const void* __restrict__ Bw,
    void* __restrict__ Cout, const bf16* __restrict__ aux,
    int Mdim, int Ndim, int Kdim) {
  __shared__ __align__(16) bf16 As[128 * 32];
  __shared__ __align__(16) bf16 Bs[128 * 32];

  const int n0 = blockIdx.x * 128;
  const int m0 = blockIdx.y * 128;
  const int t = threadIdx.x;
  const int w = t >> 6, l = t & 63;
  const int wr = w >> 1, wc = w & 1;
  const int lr = l & 15, lg = l >> 4, lk = lg * 8;

  f32x4_t acc[4][4];
  #pragma unroll
  for (int i = 0; i < 4; i++)
    #pragma unroll
    for (int j = 0; j < 4; j++) acc[i][j] = (f32x4_t){0.f, 0.f, 0.f, 0.f};

  // staging geometry: lds byte offset o = half*4096 + w*1024 + l*16
  // -> row = w*16 + l/4 (+64 for half 1), elem col = (l&3)*8
  const int rS = w * 16 + (l >> 2);
  const int cS = (l & 3) * 8;
  const bf16* Ab0 = A + (size_t)(m0 + rS) * Kdim + cS;
  const bf16* Ab1 = A + (size_t)(m0 + rS + 64) * Kdim + cS;
  const bf16* Bb0 = nullptr;
  const bf16* Bb1 = nullptr;
  if constexpr (BBF16) {
    const bf16* Bh = (const bf16*)Bw;
    Bb0 = Bh + (size_t)(n0 + rS) * Kdim + cS;
    Bb1 = Bh + (size_t)(n0 + rS + 64) * Kdim + cS;
  }
  // f32 fallback staging geometry
  const int rB = t >> 1, cB = (t & 1) * 16;
  const float* Bbf = (const float*)Bw + (size_t)(n0 + rB) * Kdim + cB;

  for (int kt = 0; kt < Kdim; kt += 32) {
    __syncthreads();  // previous fragment reads done before overwrite
    gl_lds16(Ab0 + kt, (char*)As + w * 1024);
    gl_lds16(Ab1 + kt, (char*)As + 4096 + w * 1024);
    if constexpr (BBF16) {
      gl_lds16(Bb0 + kt, (char*)Bs + w * 1024);
      gl_lds16(Bb1 + kt, (char*)Bs + 4096 + w * 1024);
    } else {
      const float4* src = (const float4*)(Bbf + kt);
      char* dstb = (char*)Bs + rB * 64 + cB * 2;
      #pragma unroll
      for (int j = 0; j < 4; j++) {
        float4 f = src[j];
        ushort4 hv;
        hv.x = f2bu(f.x); hv.y = f2bu(f.y); hv.z = f2bu(f.z); hv.w = f2bu(f.w);
        *(ushort4*)(dstb + j * 8) = hv;
      }
    }
    __syncthreads();  // drains vmcnt (global_load_lds) + lgkmcnt

    bf16x8_t af[4], bfr[4];
    #pragma unroll
    for (int i = 0; i < 4; i++) {
      af[i]  = *(const bf16x8_t*)(As + (wr * 64 + i * 16 + lr) * 32 + lk);
      bfr[i] = *(const bf16x8_t*)(Bs + (wc * 64 + i * 16 + lr) * 32 + lk);
    }
    #pragma unroll
    for (int mi = 0; mi < 4; mi++)
      #pragma unroll
      for (int ni = 0; ni < 4; ni++)
        acc[mi][ni] = mfma16(af[mi], bfr[ni], acc[mi][ni]);
  }

  // Epilogue. C/D layout: col = lane&15, row = (lane>>4)*4 + reg.
  const int row0 = m0 + wr * 64 + lg * 4;
  const int col0 = n0 + wc * 64 + lr;
  #pragma unroll
  for (int mi = 0; mi < 4; mi++) {
    #pragma unroll
    for (int ni = 0; ni < 4; ni++) {
      #pragma unroll
      for (int r = 0; r < 4; r++) {
        const int row = row0 + mi * 16 + r;
        const int col = col0 + ni * 16;
        const float v = acc[mi][ni][r];
        if constexpr (EPI == EPI_BF16) {
          ((bf16*)Cout)[(size_t)row * Ndim + col] = __float2bfloat16(v);
        } else if constexpr (EPI == EPI_F32) {
          ((float*)Cout)[(size_t)row * Ndim + col] = v;
        } else if constexpr (EPI == EPI_VT) {
          // write V transposed: vt[(b*8+kvh)][d][s], s = row%SEQ
          const int kvh = col >> 8, d = col & 255;
          const int bb = row >> 11, s = row & 2047;
          ((bf16*)Cout)[(((size_t)((bb * 8 + kvh) * 256 + d)) << 11) + s] =
              __float2bfloat16(v);
        } else {  // EPI_GELUMUL: out = gelu_tanh(aux) * acc, in-place over aux
          const float g = __bfloat162float(aux[(size_t)row * Ndim + col]);
          const float u = 0.7978845608028654f * (g + 0.044715f * g * g * g);
          const float gl = 0.5f * g * (1.f + tanhf(u));
          ((bf16*)Cout)[(size_t)row * Ndim + col] = __float2bfloat16(gl * v);
        }
      }
    }
  }
  (void)aux;
  (void)Mdim;
}

// ---------------------------------------------------------------------------
// RMSNorm of input hidden -> bf16
// ---------------------------------------------------------------------------
__global__ __launch_bounds__(256) void rmsnorm_in(
    const float* __restrict__ x, const float* __restrict__ w,
    bf16* __restrict__ out) {
  const int row = blockIdx.x, t = threadIdx.x;
  const float4* xr = (const float4*)(x + (size_t)row * HID);
  float4 v[4];
  float ss = 0.f;
  #pragma unroll
  for (int j = 0; j < 4; j++) {
    const int idx = t + 256 * j;
    if (idx < HID / 4) {
      v[j] = xr[idx];
      ss += v[j].x * v[j].x + v[j].y * v[j].y + v[j].z * v[j].z + v[j].w * v[j].w;
    }
  }
  ss = block_reduce_sum(ss);
  const float sc = rsqrtf(ss * (1.f / HID) + EPSF);
  const float4* w4 = (const float4*)w;
  bf16* orow = out + (size_t)row * HID;
  #pragma unroll
  for (int j = 0; j < 4; j++) {
    const int idx = t + 256 * j;
    if (idx < HID / 4) {
      const float4 wv = w4[idx];
      ushort4 o;
      o.x = f2bu(v[j].x * sc * (1.f + wv.x));
      o.y = f2bu(v[j].y * sc * (1.f + wv.y));
      o.z = f2bu(v[j].z * sc * (1.f + wv.z));
      o.w = f2bu(v[j].w * sc * (1.f + wv.w));
      *(ushort4*)(orow + idx * 4) = o;
    }
  }
}

// ---------------------------------------------------------------------------
// RoPE in-place on q (16 heads) and k (8 heads), bf16.
// ---------------------------------------------------------------------------
__global__ __launch_bounds__(128) void rope_kernel(
    bf16* __restrict__ q, bf16* __restrict__ k,
    const float* __restrict__ cosb, const float* __restrict__ sinb) {
  const int tok = blockIdx.x;
  const int hs = blockIdx.y;
  const int d = threadIdx.x;  // 0..127
  const int s = tok & (SEQ - 1);
  bf16* ptr = (hs < NHEADS)
                  ? q + (size_t)tok * QOUT + hs * HDIM
                  : k + (size_t)tok * KOUT + (hs - NHEADS) * HDIM;
  const float c = cosb[s * HDIM + d];
  const float sn = sinb[s * HDIM + d];
  const float x0 = __bfloat162float(ptr[d]);
  const float x1 = __bfloat162float(ptr[d + 128]);
  ptr[d] = __float2bfloat16(x0 * c - x1 * sn);
  ptr[d + 128] = __float2bfloat16(x1 * c + x0 * sn);
}

// ---------------------------------------------------------------------------
// Flash attention, sliding window 1024, softcap 50, fixed-base softmax.
// grid (SEQ/64, NHEADS, NBATCH), 4 waves; each wave owns 16 q-rows.
// ---------------------------------------------------------------------------
__global__ __launch_bounds__(256) void attn_kernel(
    const bf16* __restrict__ q, const bf16* __restrict__ k,
    const bf16* __restrict__ vt, bf16* __restrict__ out) {
  __shared__ __align__(16) bf16 plds[4][16 * 32];

  const int qt = blockIdx.x, h = blockIdx.y, b = blockIdx.z;
  const int w = threadIdx.x >> 6, l = threadIdx.x & 63;
  const int kvh = h >> 1;
  const int qbase = qt * 64 + w * 16;  // within sequence
  const int lr = l & 15, lg = l >> 4, lk = lg * 8;

  bf16x8_t qf[8];
  const bf16* qrow = q + (size_t)(b * SEQ + qbase + lr) * QOUT + h * HDIM;
  #pragma unroll
  for (int c = 0; c < 8; c++) qf[c] = *(const bf16x8_t*)(qrow + c * 32 + lk);

  f32x4_t acc[16];
  #pragma unroll
  for (int i = 0; i < 16; i++) acc[i] = (f32x4_t){0.f, 0.f, 0.f, 0.f};
  float L[4] = {0.f, 0.f, 0.f, 0.f};

  const bf16* kp = k + (size_t)(b * SEQ) * KOUT + kvh * HDIM;
  const bf16* vp = vt + (size_t)(b * NKVH + kvh) * HDIM * SEQ;
  bf16* pl = &plds[w][0];

  int kstart = qbase - 1023;
  if (kstart < 0) kstart = 0;
  kstart &= ~31;
  const int kend = qbase + 15;

  for (int kb = kstart; kb <= kend; kb += 32) {
    f32x4_t s0 = (f32x4_t){0.f, 0.f, 0.f, 0.f};
    f32x4_t s1 = (f32x4_t){0.f, 0.f, 0.f, 0.f};
    #pragma unroll
    for (int c = 0; c < 8; c++) {
      bf16x8_t k0 = *(const bf16x8_t*)(kp + (size_t)(kb + lr) * KOUT + c * 32 + lk);
      bf16x8_t k1 = *(const bf16x8_t*)(kp + (size_t)(kb + 16 + lr) * KOUT + c * 32 + lk);
      s0 = mfma16(qf[c], k0, s0);
      s1 = mfma16(qf[c], k1, s1);
    }
    float p[8];
    #pragma unroll
    for (int sub = 0; sub < 2; sub++) {
      const int j = kb + sub * 16 + lr;
      #pragma unroll
      for (int r = 0; r < 4; r++) {
        const int i = qbase + lg * 4 + r;
        float sc = (sub ? s1[r] : s0[r]) * 0.0625f;
        sc = 50.f * tanhf(sc * 0.02f);
        const bool ok = (j <= i) && (j > i - 1024);
        p[sub * 4 + r] = ok ? __expf(sc) : 0.f;
      }
    }
    #pragma unroll
    for (int r = 0; r < 4; r++) {
      float ps = p[r] + p[4 + r];
      ps += __shfl_xor(ps, 1, 64);
      ps += __shfl_xor(ps, 2, 64);
      ps += __shfl_xor(ps, 4, 64);
      ps += __shfl_xor(ps, 8, 64);
      L[r] += ps;
    }
    #pragma unroll
    for (int sub = 0; sub < 2; sub++)
      #pragma unroll
      for (int r = 0; r < 4; r++)
        pl[(lg * 4 + r) * 32 + sub * 16 + lr] = __float2bfloat16(p[sub * 4 + r]);
    asm volatile("s_waitcnt lgkmcnt(0)" ::: "memory");
    const bf16x8_t pa = *(const bf16x8_t*)(pl + lr * 32 + lk);
    #pragma unroll
    for (int dt = 0; dt < 16; dt++) {
      bf16x8_t bv = *(const bf16x8_t*)(vp + (size_t)(dt * 16 + lr) * SEQ + kb + lk);
      acc[dt] = mfma16(pa, bv, acc[dt]);
    }
  }

  float rL[4];
  #pragma unroll
  for (int r = 0; r < 4; r++) rL[r] = 1.f / L[r];
  #pragma unroll
  for (int dt = 0; dt < 16; dt++) {
    #pragma unroll
    for (int r = 0; r < 4; r++) {
      const int tok = b * SEQ + qbase + lg * 4 + r;
      out[(size_t)tok * QOUT + h * HDIM + dt * 16 + lr] =
          __float2bfloat16(acc[dt][r] * rL[r]);
    }
  }
}

// ---------------------------------------------------------------------------
// fuse1: h1 = hidden + rmsnorm(attn_proj, w_post); y = bf16(rmsnorm(h1, w_pre))
// ---------------------------------------------------------------------------
__global__ __launch_bounds__(256) void fuse_attn(
    const float* __restrict__ hidden, const float* __restrict__ ap,
    const float* __restrict__ w_post, const float* __restrict__ w_pre,
    float* __restrict__ h1, bf16* __restrict__ y) {
  const int row = blockIdx.x, t = threadIdx.x;
  const float4* ar = (const float4*)(ap + (size_t)row * HID);
  const float4* hr = (const float4*)(hidden + (size_t)row * HID);
  float4 a[4];
  float ss = 0.f;
  #pragma unroll
  for (int j = 0; j < 4; j++) {
    const int idx = t + 256 * j;
    if (idx < HID / 4) {
      a[j] = ar[idx];
      ss += a[j].x * a[j].x + a[j].y * a[j].y + a[j].z * a[j].z + a[j].w * a[j].w;
    }
  }
  ss = block_reduce_sum(ss);
  const float sc = rsqrtf(ss * (1.f / HID) + EPSF);
  const float4* wpo = (const float4*)w_post;
  float4* h1r = (float4*)(h1 + (size_t)row * HID);
  float4 hv[4];
  float ss2 = 0.f;
  #pragma unroll
  for (int j = 0; j < 4; j++) {
    const int idx = t + 256 * j;
    if (idx < HID / 4) {
      const float4 wv = wpo[idx];
      const float4 x = hr[idx];
      hv[j].x = x.x + a[j].x * sc * (1.f + wv.x);
      hv[j].y = x.y + a[j].y * sc * (1.f + wv.y);
      hv[j].z = x.z + a[j].z * sc * (1.f + wv.z);
      hv[j].w = x.w + a[j].w * sc * (1.f + wv.w);
      ss2 += hv[j].x * hv[j].x + hv[j].y * hv[j].y + hv[j].z * hv[j].z + hv[j].w * hv[j].w;
      h1r[idx] = hv[j];
    }
  }
  ss2 = block_reduce_sum(ss2);
  const float sc2 = rsqrtf(ss2 * (1.f / HID) + EPSF);
  const float4* wpr = (const float4*)w_pre;
  bf16* yr = y + (size_t)row * HID;
  #pragma unroll
  for (int j = 0; j < 4; j++) {
    const int idx = t + 256 * j;
    if (idx < HID / 4) {
      const float4 wv = wpr[idx];
      ushort4 o;
      o.x = f2bu(hv[j].x * sc2 * (1.f + wv.x));
      o.y = f2bu(hv[j].y * sc2 * (1.f + wv.y));
      o.z = f2bu(hv[j].z * sc2 * (1.f + wv.z));
      o.w = f2bu(hv[j].w * sc2 * (1.f + wv.w));
      *(ushort4*)(yr + idx * 4) = o;
    }
  }
}

// ---------------------------------------------------------------------------
// fuse2: out = h1 + rmsnorm(mlp, w_post_ff)
// ---------------------------------------------------------------------------
__global__ __launch_bounds__(256) void fuse_out(
    const float* __restrict__ h1, const float* __restrict__ mlp,
    const float* __restrict__ w, float* __restrict__ out) {
  const int row = blockIdx.x, t = threadIdx.x;
  const float4* mr = (const float4*)(mlp + (size_t)row * HID);
  float4 m[4];
  float ss = 0.f;
  #pragma unroll
  for (int j = 0; j < 4; j++) {
    const int idx = t + 256 * j;
    if (idx < HID / 4) {
      m[j] = mr[idx];
      ss += m[j].x * m[j].x + m[j].y * m[j].y + m[j].z * m[j].z + m[j].w * m[j].w;
    }
  }
  ss = block_reduce_sum(ss);
  const float sc = rsqrtf(ss * (1.f / HID) + EPSF);
  const float4* hr = (const float4*)(h1 + (size_t)row * HID);
  const float4* w4 = (const float4*)w;
  float4* orow = (float4*)(out + (size_t)row * HID);
  #pragma unroll
  for (int j = 0; j < 4; j++) {
    const int idx = t + 256 * j;
    if (idx < HID / 4) {
      const float4 wv = w4[idx];
      const float4 x = hr[idx];
      float4 o;
      o.x = x.x + m[j].x * sc * (1.f + wv.x);
      o.y = x.y + m[j].y * sc * (1.f + wv.y);
      o.z = x.z + m[j].z * sc * (1.f + wv.z);
      o.w = x.w + m[j].w * sc * (1.f + wv.w);
      orow[idx] = o;
    }
  }
}

// ---------------------------------------------------------------------------
extern "C" void kernel_launch(void* const* d_in, const int* in_sizes, int n_in,
                              void* d_out, int out_size, void* d_ws,
                              size_t ws_size, hipStream_t stream) {
  const float* hidden = (const float*)d_in[0];
  const float* cosb = (const float*)d_in[1];
  const float* sinb = (const float*)d_in[2];
  const float* Wq = (const float*)d_in[3];
  const float* Wk = (const float*)d_in[4];
  const float* Wv = (const float*)d_in[5];
  const float* Wo = (const float*)d_in[6];
  const float* Wgate = (const float*)d_in[7];
  const float* Wup = (const float*)d_in[8];
  const float* Wdown = (const float*)d_in[9];
  const float* w_in = (const float*)d_in[10];
  const float* w_post_attn = (const float*)d_in[11];
  const float* w_pre_ff = (const float*)d_in[12];
  const float* w_post_ff = (const float*)d_in[13];
  float* out = (float*)d_out;

  (void)in_sizes; (void)n_in; (void)out_size;

  const size_t WB = 102760448;        // 14336*3584*2 — bf16 weight scratch
  const size_t ACT = 276824064;       // activation region total
  const bool bfw = (ws_size >= WB + ACT);

  char* ws = (char*)d_ws;
  bf16* wbuf = (bf16*)ws;             // only used when bfw
  char* ab = ws + (bfw ? WB : 0);     // activation base

  // Region 0 (63 MB): xn + q -> attn_proj -> mlp
  bf16* xn = (bf16*)(ab);
  bf16* q = (bf16*)(ab + 29360128);
  float* attn_proj = (float*)(ab);
  float* mlp = (float*)(ab);
  // Region 1 (67 MB): k + vt + attn_out -> h1
  bf16* kbuf = (bf16*)(ab + 62914560);
  bf16* vt = (bf16*)(ab + 62914560 + 16777216);
  bf16* attn_out = (bf16*)(ab + 62914560 + 33554432);
  float* h1 = (float*)(ab + 62914560);
  // Region 2: y
  bf16* y = (bf16*)(ab + 130023424);
  // Region 3: gate (gelu*up written in-place)
  bf16* gate = (bf16*)(ab + 159383552);

  rmsnorm_in<<<MTOK, 256, 0, stream>>>(hidden, w_in, xn);

  if (bfw) {
    cvt_w<<<4096, 256, 0, stream>>>(Wq, wbuf, QOUT * HID);
    gemm_bt<EPI_BF16, true><<<dim3(QOUT / 128, MTOK / 128), 256, 0, stream>>>(
        xn, wbuf, q, nullptr, MTOK, QOUT, HID);
    cvt_w<<<4096, 256, 0, stream>>>(Wk, wbuf, KOUT * HID);
    gemm_bt<EPI_BF16, true><<<dim3(KOUT / 128, MTOK / 128), 256, 0, stream>>>(
        xn, wbuf, kbuf, nullptr, MTOK, KOUT, HID);
    cvt_w<<<4096, 256, 0, stream>>>(Wv, wbuf, KOUT * HID);
    gemm_bt<EPI_VT, true><<<dim3(KOUT / 128, MTOK / 128), 256, 0, stream>>>(
        xn, wbuf, vt, nullptr, MTOK, KOUT, HID);
    rope_kernel<<<dim3(MTOK, NHEADS + NKVH), 128, 0, stream>>>(q, kbuf, cosb, sinb);
    attn_kernel<<<dim3(SEQ / 64, NHEADS, NBATCH), 256, 0, stream>>>(
        q, kbuf, vt, attn_out);
    cvt_w<<<4096, 256, 0, stream>>>(Wo, wbuf, HID * QOUT);
    gemm_bt<EPI_F32, true><<<dim3(HID / 128, MTOK / 128), 256, 0, stream>>>(
        attn_out, wbuf, attn_proj, nullptr, MTOK, HID, QOUT);
    fuse_attn<<<MTOK, 256, 0, stream>>>(hidden, attn_proj, w_post_attn,
                                        w_pre_ff, h1, y);
    cvt_w<<<4096, 256, 0, stream>>>(Wgate, wbuf, INTERD * HID);
    gemm_bt<EPI_BF16, true><<<dim3(INTERD / 128, MTOK / 128), 256, 0, stream>>>(
        y, wbuf, gate, nullptr, MTOK, INTERD, HID);
    cvt_w<<<4096, 256, 0, stream>>>(Wup, wbuf, INTERD * HID);
    gemm_bt<EPI_GELUMUL, true><<<dim3(INTERD / 128, MTOK / 128), 256, 0, stream>>>(
        y, wbuf, gate, gate, MTOK, INTERD, HID);
    cvt_w<<<4096, 256, 0, stream>>>(Wdown, wbuf, HID * INTERD);
    gemm_bt<EPI_F32, true><<<dim3(HID / 128, MTOK / 128), 256, 0, stream>>>(
        gate, wbuf, mlp, nullptr, MTOK, HID, INTERD);
  } else {
    gemm_bt<EPI_BF16, false><<<dim3(QOUT / 128, MTOK / 128), 256, 0, stream>>>(
        xn, Wq, q, nullptr, MTOK, QOUT, HID);
    gemm_bt<EPI_BF16, false><<<dim3(KOUT / 128, MTOK / 128), 256, 0, stream>>>(
        xn, Wk, kbuf, nullptr, MTOK, KOUT, HID);
    gemm_bt<EPI_VT, false><<<dim3(KOUT / 128, MTOK / 128), 256, 0, stream>>>(
        xn, Wv, vt, nullptr, MTOK, KOUT, HID);
    rope_kernel<<<dim3(MTOK, NHEADS + NKVH), 128, 0, stream>>>(q, kbuf, cosb, sinb);
    attn_kernel<<<dim3(SEQ / 64, NHEADS, NBATCH), 256, 0, stream>>>(
        q, kbuf, vt, attn_out);
    gemm_bt<EPI_F32, false><<<dim3(HID / 128, MTOK / 128), 256, 0, stream>>>(
        attn_out, Wo, attn_proj, nullptr, MTOK, HID, QOUT);
    fuse_attn<<<MTOK, 256, 0, stream>>>(hidden, attn_proj, w_post_attn,
                                        w_pre_ff, h1, y);
    gemm_bt<EPI_BF16, false><<<dim3(INTERD / 128, MTOK / 128), 256, 0, stream>>>(
        y, Wgate, gate, nullptr, MTOK, INTERD, HID);
    gemm_bt<EPI_GELUMUL, false><<<dim3(INTERD / 128, MTOK / 128), 256, 0, stream>>>(
        y, Wup, gate, gate, MTOK, INTERD, HID);
    gemm_bt<EPI_F32, false><<<dim3(HID / 128, MTOK / 128), 256, 0, stream>>>(
        gate, Wdown, mlp, nullptr, MTOK, HID, INTERD);
  }

  fuse_out<<<MTOK, 256, 0, stream>>>(h1, mlp, w_post_ff, out);
}

// Round 4
// 2639.092 us; speedup vs baseline: 1.5152x; 1.2620x over previous
//
#include <hip/hip_runtime.h>
#include <hip/hip_bf16.h>

typedef __hip_bfloat16 bf16;
typedef __bf16 bf16x8_t __attribute__((ext_vector_type(8)));
typedef float f32x4_t __attribute__((ext_vector_type(4)));
typedef unsigned short u16x8_t __attribute__((ext_vector_type(8)));

#define HID 3584
#define SEQ 2048
#define NBATCH 2
#define MTOK 4096
#define NHEADS 16
#define NKVH 8
#define HDIM 256
#define QOUT 4096
#define KOUT 2048
#define INTERD 14336
#define EPSF 1e-6f

static __device__ __forceinline__ unsigned short f2bu(float f) {
  union { bf16 b; unsigned short u; } cv;
  cv.b = __float2bfloat16(f);
  return cv.u;
}

static __device__ __forceinline__ f32x4_t mfma16(bf16x8_t a, bf16x8_t b, f32x4_t c) {
  return __builtin_amdgcn_mfma_f32_16x16x32_bf16(a, b, c, 0, 0, 0);
}

static __device__ __forceinline__ void gl_lds16(const void* g, void* l) {
  __builtin_amdgcn_global_load_lds((__attribute__((address_space(1))) void*)g,
                                   (__attribute__((address_space(3))) void*)l,
                                   16, 0, 0);
}

static __device__ __forceinline__ float block_reduce_sum(float v) {
  __shared__ float buf[4];
  #pragma unroll
  for (int m = 1; m < 64; m <<= 1) v += __shfl_xor(v, m, 64);
  __syncthreads();
  if ((threadIdx.x & 63) == 0) buf[threadIdx.x >> 6] = v;
  __syncthreads();
  return buf[0] + buf[1] + buf[2] + buf[3];
}

// ---------------------------------------------------------------------------
// weight convert: f32 -> bf16
// ---------------------------------------------------------------------------
__global__ __launch_bounds__(256) void cvt_w(
    const float* __restrict__ src, bf16* __restrict__ dst, int n) {
  const int stride = gridDim.x * 256 * 8;
  for (int i = (blockIdx.x * 256 + threadIdx.x) * 8; i < n; i += stride) {
    const float4 a = *(const float4*)(src + i);
    const float4 b = *(const float4*)(src + i + 4);
    u16x8_t o;
    o[0] = f2bu(a.x); o[1] = f2bu(a.y); o[2] = f2bu(a.z); o[3] = f2bu(a.w);
    o[4] = f2bu(b.x); o[5] = f2bu(b.y); o[6] = f2bu(b.z); o[7] = f2bu(b.w);
    *(u16x8_t*)(dst + i) = o;
  }
}

// ---------------------------------------------------------------------------
// 8-phase 256x256 GEMM: C[M=4096][N] = A[M][K](bf16) * B[N][K](bf16)^T
// 8 waves (2Mx4N), BK=64, 2-deep LDS double-buffer, T2 swizzle, counted vmcnt.
// RACE FIX vs R3: tile entry is now {vmcnt(N); s_barrier; sched_barrier} —
// per-wave vmcnt alone does NOT order other waves' global_load_lds writes
// against this wave's ds_reads; the barrier publishes them.
// ---------------------------------------------------------------------------
enum { EPI_BF16 = 0, EPI_F32 = 1, EPI_VT = 2, EPI_GELUMUL = 3 };

template <int EPI>
__global__ __launch_bounds__(512, 2) void gemm8p(
    const bf16* __restrict__ A, const bf16* __restrict__ Bw,
    void* __restrict__ Cout, const bf16* __restrict__ aux,
    int Ndim, int Kdim) {
  __shared__ __align__(16) char L[131072];  // [buf2][op2][row256][col64] bf16

  const int NT = Kdim >> 6;
  const int NB = gridDim.x;
  const int bid = blockIdx.x;
  // XCD-bijective swizzle (NB%8==0 for all shapes), B-panel-major ordering:
  const int sw = (bid & 7) * (NB >> 3) + (bid >> 3);
  const int m0 = (sw & 15) * 256;  // M = 4096 -> 16 M-tiles, fastest
  const int n0 = (sw >> 4) * 256;

  const int tid = threadIdx.x;
  const int wid = tid >> 6, l = tid & 63;
  const int wm = wid >> 2, wn = wid & 3;
  const int lr = l & 15, lg = l >> 4;

  // --- staging geometry (linear LDS dest, inverse-swizzled global src) ---
  const int rlane = wid * 16 + (l >> 3);        // row within 128-row half
  const int lc8 = (((l & 7) ^ (l >> 3)) << 3);  // swizzled source col (elems)
  const bf16* srcA = A + (size_t)(m0 + rlane) * Kdim + lc8;
  const bf16* srcB = Bw + (size_t)(n0 + rlane) * Kdim + lc8;
  const size_t K128 = (size_t)Kdim << 7;  // 128 rows of elems
  const size_t K8 = (size_t)Kdim << 3;    // 8 rows

  auto STAGE = [&](int op, int rh, int tl) {
    if (tl >= NT) return;
    const bf16* s = (op ? srcB : srcA) + (size_t)rh * K128 + ((size_t)tl << 6);
    char* d = L + ((tl & 1) << 16) + (op << 15) + (rh << 14) + (wid << 11);
    gl_lds16(s, d);
    gl_lds16(s + K8, d + 1024);
  };

  // --- fragment read geometry (swizzled) ---
  const int arow = wm * 128 + lr;
  const int brow = wn * 64 + lr;
  const int swz = lr & 7;
  const int csw0 = ((0 * 4 + lg) ^ swz) << 4;
  const int csw1 = ((1 * 4 + lg) ^ swz) << 4;
  auto LDA = [&](int mi, int kk, int c) {
    return *(const bf16x8_t*)(L + (c << 16) + arow * 128 + mi * 2048 +
                              (kk ? csw1 : csw0));
  };
  auto LDB = [&](int ni, int kk, int c) {
    return *(const bf16x8_t*)(L + (c << 16) + 32768 + brow * 128 + ni * 2048 +
                              (kk ? csw1 : csw0));
  };

  f32x4_t acc[8][4];
  #pragma unroll
  for (int i = 0; i < 8; i++)
    #pragma unroll
    for (int j = 0; j < 4; j++) acc[i][j] = (f32x4_t){0.f, 0.f, 0.f, 0.f};

  bf16x8_t fa[8][2], fb[4][2];

  // prologue: B0(0),B1(0),A0(0),A1(0), B0(1),B1(1),A0(1)  (7 halves, 14 loads)
  STAGE(1, 0, 0); STAGE(1, 1, 0); STAGE(0, 0, 0); STAGE(0, 1, 0);
  STAGE(1, 0, 1); STAGE(1, 1, 1); STAGE(0, 0, 1);

#define MFMA_Q(MB, NBQ)                                                        \
  _Pragma("unroll") for (int mi = 0; mi < 4; ++mi)                             \
  _Pragma("unroll") for (int ni = 0; ni < 2; ++ni) {                           \
    acc[MB + mi][NBQ + ni] =                                                   \
        mfma16(fa[MB + mi][0], fb[NBQ + ni][0], acc[MB + mi][NBQ + ni]);       \
    acc[MB + mi][NBQ + ni] =                                                   \
        mfma16(fa[MB + mi][1], fb[NBQ + ni][1], acc[MB + mi][NBQ + ni]);       \
  }

#define TILE(T, C)                                                             \
  {                                                                            \
    if ((T) + 1 < NT) asm volatile("s_waitcnt vmcnt(6)" ::: "memory");         \
    else asm volatile("s_waitcnt vmcnt(0)" ::: "memory");                      \
    __builtin_amdgcn_s_barrier(); /* publish all waves' tile-T LDS writes */   \
    __builtin_amdgcn_sched_barrier(0);                                         \
    /* phase 0: all A-low + all B frags; stage A1(t+1) */                      \
    _Pragma("unroll") for (int mi = 0; mi < 4; ++mi) {                         \
      fa[mi][0] = LDA(mi, 0, (C)); fa[mi][1] = LDA(mi, 1, (C));                \
    }                                                                          \
    _Pragma("unroll") for (int ni = 0; ni < 4; ++ni) {                         \
      fb[ni][0] = LDB(ni, 0, (C)); fb[ni][1] = LDB(ni, 1, (C));                \
    }                                                                          \
    STAGE(0, 1, (T) + 1);                                                      \
    __builtin_amdgcn_s_barrier();                                              \
    asm volatile("s_waitcnt lgkmcnt(0)" ::: "memory");                         \
    __builtin_amdgcn_sched_barrier(0);                                         \
    __builtin_amdgcn_s_setprio(1);                                             \
    MFMA_Q(0, 0);                                                              \
    __builtin_amdgcn_s_setprio(0);                                             \
    __builtin_amdgcn_s_barrier();                                              \
    /* phase 1: stage B0(t+2) into active (B regions dead) */                  \
    STAGE(1, 0, (T) + 2);                                                      \
    __builtin_amdgcn_s_barrier();                                              \
    __builtin_amdgcn_s_setprio(1);                                             \
    MFMA_Q(0, 2);                                                              \
    __builtin_amdgcn_s_setprio(0);                                             \
    __builtin_amdgcn_s_barrier();                                              \
    /* phase 2: A-high frags; stage B1(t+2) */                                 \
    _Pragma("unroll") for (int mi = 0; mi < 4; ++mi) {                         \
      fa[4 + mi][0] = LDA(4 + mi, 0, (C)); fa[4 + mi][1] = LDA(4 + mi, 1, (C));\
    }                                                                          \
    STAGE(1, 1, (T) + 2);                                                      \
    __builtin_amdgcn_s_barrier();                                              \
    asm volatile("s_waitcnt lgkmcnt(0)" ::: "memory");                         \
    __builtin_amdgcn_sched_barrier(0);                                         \
    __builtin_amdgcn_s_setprio(1);                                             \
    MFMA_Q(4, 0);                                                              \
    __builtin_amdgcn_s_setprio(0);                                             \
    __builtin_amdgcn_s_barrier();                                              \
    /* phase 3: stage A0(t+2) (A regions dead after ph2) */                    \
    STAGE(0, 0, (T) + 2);                                                      \
    __builtin_amdgcn_s_barrier();                                              \
    __builtin_amdgcn_s_setprio(1);                                             \
    MFMA_Q(4, 2);                                                              \
    __builtin_amdgcn_s_setprio(0);                                             \
    __builtin_amdgcn_s_barrier();                                              \
  }

  for (int t = 0; t < NT; t += 2) {
    TILE(t, 0);
    TILE(t + 1, 1);
  }
#undef TILE
#undef MFMA_Q

  // Epilogue. C/D layout: col = lane&15, row = (lane>>4)*4 + reg.
  const int row0 = m0 + wm * 128 + lg * 4;
  const int col0 = n0 + wn * 64 + lr;
  #pragma unroll
  for (int mi = 0; mi < 8; mi++) {
    #pragma unroll
    for (int ni = 0; ni < 4; ni++) {
      #pragma unroll
      for (int r = 0; r < 4; r++) {
        const int row = row0 + mi * 16 + r;
        const int col = col0 + ni * 16;
        const float v = acc[mi][ni][r];
        if constexpr (EPI == EPI_BF16) {
          ((bf16*)Cout)[(size_t)row * Ndim + col] = __float2bfloat16(v);
        } else if constexpr (EPI == EPI_F32) {
          ((float*)Cout)[(size_t)row * Ndim + col] = v;
        } else if constexpr (EPI == EPI_VT) {
          // write V transposed: vt[(b*8+kvh)][d][s]
          const int kvh = col >> 8, d = col & 255;
          const int bb = row >> 11, s = row & 2047;
          ((bf16*)Cout)[(((size_t)((bb * 8 + kvh) * 256 + d)) << 11) + s] =
              __float2bfloat16(v);
        } else {  // EPI_GELUMUL
          const float g = __bfloat162float(aux[(size_t)row * Ndim + col]);
          const float u = 0.7978845608028654f * (g + 0.044715f * g * g * g);
          const float gl = 0.5f * g * (1.f + tanhf(u));
          ((bf16*)Cout)[(size_t)row * Ndim + col] = __float2bfloat16(gl * v);
        }
      }
    }
  }
  (void)aux;
}

// ---------------------------------------------------------------------------
// RMSNorm of input hidden -> bf16
// ---------------------------------------------------------------------------
__global__ __launch_bounds__(256) void rmsnorm_in(
    const float* __restrict__ x, const float* __restrict__ w,
    bf16* __restrict__ out) {
  const int row = blockIdx.x, t = threadIdx.x;
  const float4* xr = (const float4*)(x + (size_t)row * HID);
  float4 v[4];
  float ss = 0.f;
  #pragma unroll
  for (int j = 0; j < 4; j++) {
    const int idx = t + 256 * j;
    if (idx < HID / 4) {
      v[j] = xr[idx];
      ss += v[j].x * v[j].x + v[j].y * v[j].y + v[j].z * v[j].z + v[j].w * v[j].w;
    }
  }
  ss = block_reduce_sum(ss);
  const float sc = rsqrtf(ss * (1.f / HID) + EPSF);
  const float4* w4 = (const float4*)w;
  bf16* orow = out + (size_t)row * HID;
  #pragma unroll
  for (int j = 0; j < 4; j++) {
    const int idx = t + 256 * j;
    if (idx < HID / 4) {
      const float4 wv = w4[idx];
      ushort4 o;
      o.x = f2bu(v[j].x * sc * (1.f + wv.x));
      o.y = f2bu(v[j].y * sc * (1.f + wv.y));
      o.z = f2bu(v[j].z * sc * (1.f + wv.z));
      o.w = f2bu(v[j].w * sc * (1.f + wv.w));
      *(ushort4*)(orow + idx * 4) = o;
    }
  }
}

// ---------------------------------------------------------------------------
// RoPE in-place on q (16 heads) and k (8 heads), bf16.
// ---------------------------------------------------------------------------
__global__ __launch_bounds__(128) void rope_kernel(
    bf16* __restrict__ q, bf16* __restrict__ k,
    const float* __restrict__ cosb, const float* __restrict__ sinb) {
  const int tok = blockIdx.x;
  const int hs = blockIdx.y;
  const int d = threadIdx.x;  // 0..127
  const int s = tok & (SEQ - 1);
  bf16* ptr = (hs < NHEADS)
                  ? q + (size_t)tok * QOUT + hs * HDIM
                  : k + (size_t)tok * KOUT + (hs - NHEADS) * HDIM;
  const float c = cosb[s * HDIM + d];
  const float sn = sinb[s * HDIM + d];
  const float x0 = __bfloat162float(ptr[d]);
  const float x1 = __bfloat162float(ptr[d + 128]);
  ptr[d] = __float2bfloat16(x0 * c - x1 * sn);
  ptr[d + 128] = __float2bfloat16(x1 * c + x0 * sn);
}

// ---------------------------------------------------------------------------
// Flash attention, sliding window 1024, softcap 50, fixed-base softmax.
// ---------------------------------------------------------------------------
__global__ __launch_bounds__(256) void attn_kernel(
    const bf16* __restrict__ q, const bf16* __restrict__ k,
    const bf16* __restrict__ vt, bf16* __restrict__ out) {
  __shared__ __align__(16) bf16 plds[4][16 * 32];

  const int qt = blockIdx.x, h = blockIdx.y, b = blockIdx.z;
  const int w = threadIdx.x >> 6, l = threadIdx.x & 63;
  const int kvh = h >> 1;
  const int qbase = qt * 64 + w * 16;
  const int lr = l & 15, lg = l >> 4, lk = lg * 8;

  bf16x8_t qf[8];
  const bf16* qrow = q + (size_t)(b * SEQ + qbase + lr) * QOUT + h * HDIM;
  #pragma unroll
  for (int c = 0; c < 8; c++) qf[c] = *(const bf16x8_t*)(qrow + c * 32 + lk);

  f32x4_t acc[16];
  #pragma unroll
  for (int i = 0; i < 16; i++) acc[i] = (f32x4_t){0.f, 0.f, 0.f, 0.f};
  float L[4] = {0.f, 0.f, 0.f, 0.f};

  const bf16* kp = k + (size_t)(b * SEQ) * KOUT + kvh * HDIM;
  const bf16* vp = vt + (size_t)(b * NKVH + kvh) * HDIM * SEQ;
  bf16* pl = &plds[w][0];

  int kstart = qbase - 1023;
  if (kstart < 0) kstart = 0;
  kstart &= ~31;
  const int kend = qbase + 15;

  for (int kb = kstart; kb <= kend; kb += 32) {
    f32x4_t s0 = (f32x4_t){0.f, 0.f, 0.f, 0.f};
    f32x4_t s1 = (f32x4_t){0.f, 0.f, 0.f, 0.f};
    #pragma unroll
    for (int c = 0; c < 8; c++) {
      bf16x8_t k0 = *(const bf16x8_t*)(kp + (size_t)(kb + lr) * KOUT + c * 32 + lk);
      bf16x8_t k1 = *(const bf16x8_t*)(kp + (size_t)(kb + 16 + lr) * KOUT + c * 32 + lk);
      s0 = mfma16(qf[c], k0, s0);
      s1 = mfma16(qf[c], k1, s1);
    }
    float p[8];
    #pragma unroll
    for (int sub = 0; sub < 2; sub++) {
      const int j = kb + sub * 16 + lr;
      #pragma unroll
      for (int r = 0; r < 4; r++) {
        const int i = qbase + lg * 4 + r;
        float sc = (sub ? s1[r] : s0[r]) * 0.0625f;
        sc = 50.f * tanhf(sc * 0.02f);
        const bool ok = (j <= i) && (j > i - 1024);
        p[sub * 4 + r] = ok ? __expf(sc) : 0.f;
      }
    }
    #pragma unroll
    for (int r = 0; r < 4; r++) {
      float ps = p[r] + p[4 + r];
      ps += __shfl_xor(ps, 1, 64);
      ps += __shfl_xor(ps, 2, 64);
      ps += __shfl_xor(ps, 4, 64);
      ps += __shfl_xor(ps, 8, 64);
      L[r] += ps;
    }
    #pragma unroll
    for (int sub = 0; sub < 2; sub++)
      #pragma unroll
      for (int r = 0; r < 4; r++)
        pl[(lg * 4 + r) * 32 + sub * 16 + lr] = __float2bfloat16(p[sub * 4 + r]);
    asm volatile("s_waitcnt lgkmcnt(0)" ::: "memory");
    const bf16x8_t pa = *(const bf16x8_t*)(pl + lr * 32 + lk);
    #pragma unroll
    for (int dt = 0; dt < 16; dt++) {
      bf16x8_t bv = *(const bf16x8_t*)(vp + (size_t)(dt * 16 + lr) * SEQ + kb + lk);
      acc[dt] = mfma16(pa, bv, acc[dt]);
    }
  }

  float rL[4];
  #pragma unroll
  for (int r = 0; r < 4; r++) rL[r] = 1.f / L[r];
  #pragma unroll
  for (int dt = 0; dt < 16; dt++) {
    #pragma unroll
    for (int r = 0; r < 4; r++) {
      const int tok = b * SEQ + qbase + lg * 4 + r;
      out[(size_t)tok * QOUT + h * HDIM + dt * 16 + lr] =
          __float2bfloat16(acc[dt][r] * rL[r]);
    }
  }
}

// ---------------------------------------------------------------------------
// fuse1: h1 = hidden + rmsnorm(attn_proj, w_post); y = bf16(rmsnorm(h1, w_pre))
// ---------------------------------------------------------------------------
__global__ __launch_bounds__(256) void fuse_attn(
    const float* __restrict__ hidden, const float* __restrict__ ap,
    const float* __restrict__ w_post, const float* __restrict__ w_pre,
    float* __restrict__ h1, bf16* __restrict__ y) {
  const int row = blockIdx.x, t = threadIdx.x;
  const float4* ar = (const float4*)(ap + (size_t)row * HID);
  const float4* hr = (const float4*)(hidden + (size_t)row * HID);
  float4 a[4];
  float ss = 0.f;
  #pragma unroll
  for (int j = 0; j < 4; j++) {
    const int idx = t + 256 * j;
    if (idx < HID / 4) {
      a[j] = ar[idx];
      ss += a[j].x * a[j].x + a[j].y * a[j].y + a[j].z * a[j].z + a[j].w * a[j].w;
    }
  }
  ss = block_reduce_sum(ss);
  const float sc = rsqrtf(ss * (1.f / HID) + EPSF);
  const float4* wpo = (const float4*)w_post;
  float4* h1r = (float4*)(h1 + (size_t)row * HID);
  float4 hv[4];
  float ss2 = 0.f;
  #pragma unroll
  for (int j = 0; j < 4; j++) {
    const int idx = t + 256 * j;
    if (idx < HID / 4) {
      const float4 wv = wpo[idx];
      const float4 x = hr[idx];
      hv[j].x = x.x + a[j].x * sc * (1.f + wv.x);
      hv[j].y = x.y + a[j].y * sc * (1.f + wv.y);
      hv[j].z = x.z + a[j].z * sc * (1.f + wv.z);
      hv[j].w = x.w + a[j].w * sc * (1.f + wv.w);
      ss2 += hv[j].x * hv[j].x + hv[j].y * hv[j].y + hv[j].z * hv[j].z + hv[j].w * hv[j].w;
      h1r[idx] = hv[j];
    }
  }
  ss2 = block_reduce_sum(ss2);
  const float sc2 = rsqrtf(ss2 * (1.f / HID) + EPSF);
  const float4* wpr = (const float4*)w_pre;
  bf16* yr = y + (size_t)row * HID;
  #pragma unroll
  for (int j = 0; j < 4; j++) {
    const int idx = t + 256 * j;
    if (idx < HID / 4) {
      const float4 wv = wpr[idx];
      ushort4 o;
      o.x = f2bu(hv[j].x * sc2 * (1.f + wv.x));
      o.y = f2bu(hv[j].y * sc2 * (1.f + wv.y));
      o.z = f2bu(hv[j].z * sc2 * (1.f + wv.z));
      o.w = f2bu(hv[j].w * sc2 * (1.f + wv.w));
      *(ushort4*)(yr + idx * 4) = o;
    }
  }
}

// ---------------------------------------------------------------------------
// fuse2: out = h1 + rmsnorm(mlp, w_post_ff)
// ---------------------------------------------------------------------------
__global__ __launch_bounds__(256) void fuse_out(
    const float* __restrict__ h1, const float* __restrict__ mlp,
    const float* __restrict__ w, float* __restrict__ out) {
  const int row = blockIdx.x, t = threadIdx.x;
  const float4* mr = (const float4*)(mlp + (size_t)row * HID);
  float4 m[4];
  float ss = 0.f;
  #pragma unroll
  for (int j = 0; j < 4; j++) {
    const int idx = t + 256 * j;
    if (idx < HID / 4) {
      m[j] = mr[idx];
      ss += m[j].x * m[j].x + m[j].y * m[j].y + m[j].z * m[j].z + m[j].w * m[j].w;
    }
  }
  ss = block_reduce_sum(ss);
  const float sc = rsqrtf(ss * (1.f / HID) + EPSF);
  const float4* hr = (const float4*)(h1 + (size_t)row * HID);
  const float4* w4 = (const float4*)w;
  float4* orow = (float4*)(out + (size_t)row * HID);
  #pragma unroll
  for (int j = 0; j < 4; j++) {
    const int idx = t + 256 * j;
    if (idx < HID / 4) {
      const float4 wv = w4[idx];
      const float4 x = hr[idx];
      float4 o;
      o.x = x.x + m[j].x * sc * (1.f + wv.x);
      o.y = x.y + m[j].y * sc * (1.f + wv.y);
      o.z = x.z + m[j].z * sc * (1.f + wv.z);
      o.w = x.w + m[j].w * sc * (1.f + wv.w);
      orow[idx] = o;
    }
  }
}

// ---------------------------------------------------------------------------
extern "C" void kernel_launch(void* const* d_in, const int* in_sizes, int n_in,
                              void* d_out, int out_size, void* d_ws,
                              size_t ws_size, hipStream_t stream) {
  const float* hidden = (const float*)d_in[0];
  const float* cosb = (const float*)d_in[1];
  const float* sinb = (const float*)d_in[2];
  const float* Wq = (const float*)d_in[3];
  const float* Wk = (const float*)d_in[4];
  const float* Wv = (const float*)d_in[5];
  const float* Wo = (const float*)d_in[6];
  const float* Wgate = (const float*)d_in[7];
  const float* Wup = (const float*)d_in[8];
  const float* Wdown = (const float*)d_in[9];
  const float* w_in = (const float*)d_in[10];
  const float* w_post_attn = (const float*)d_in[11];
  const float* w_pre_ff = (const float*)d_in[12];
  const float* w_post_ff = (const float*)d_in[13];
  float* out = (float*)d_out;

  (void)in_sizes; (void)n_in; (void)out_size; (void)ws_size;

  const size_t WB = 102760448;  // 14336*3584*2 — bf16 weight scratch
  char* ws = (char*)d_ws;
  bf16* wbuf = (bf16*)ws;
  char* ab = ws + WB;

  // Region 0 (63 MB): xn + q -> attn_proj -> mlp
  bf16* xn = (bf16*)(ab);
  bf16* q = (bf16*)(ab + 29360128);
  float* attn_proj = (float*)(ab);
  float* mlp = (float*)(ab);
  // Region 1 (67 MB): k + vt + attn_out -> h1
  bf16* kbuf = (bf16*)(ab + 62914560);
  bf16* vt = (bf16*)(ab + 62914560 + 16777216);
  bf16* attn_out = (bf16*)(ab + 62914560 + 33554432);
  float* h1 = (float*)(ab + 62914560);
  // Region 2: y
  bf16* y = (bf16*)(ab + 130023424);
  // Region 3: gate (gelu*up written in-place)
  bf16* gate = (bf16*)(ab + 159383552);

  rmsnorm_in<<<MTOK, 256, 0, stream>>>(hidden, w_in, xn);

  cvt_w<<<4096, 256, 0, stream>>>(Wq, wbuf, QOUT * HID);
  gemm8p<EPI_BF16><<<(QOUT / 256) * 16, 512, 0, stream>>>(
      xn, wbuf, q, nullptr, QOUT, HID);
  cvt_w<<<4096, 256, 0, stream>>>(Wk, wbuf, KOUT * HID);
  gemm8p<EPI_BF16><<<(KOUT / 256) * 16, 512, 0, stream>>>(
      xn, wbuf, kbuf, nullptr, KOUT, HID);
  cvt_w<<<4096, 256, 0, stream>>>(Wv, wbuf, KOUT * HID);
  gemm8p<EPI_VT><<<(KOUT / 256) * 16, 512, 0, stream>>>(
      xn, wbuf, vt, nullptr, KOUT, HID);
  rope_kernel<<<dim3(MTOK, NHEADS + NKVH), 128, 0, stream>>>(q, kbuf, cosb, sinb);
  attn_kernel<<<dim3(SEQ / 64, NHEADS, NBATCH), 256, 0, stream>>>(
      q, kbuf, vt, attn_out);
  cvt_w<<<4096, 256, 0, stream>>>(Wo, wbuf, HID * QOUT);
  gemm8p<EPI_F32><<<(HID / 256) * 16, 512, 0, stream>>>(
      attn_out, wbuf, attn_proj, nullptr, HID, QOUT);
  fuse_attn<<<MTOK, 256, 0, stream>>>(hidden, attn_proj, w_post_attn,
                                      w_pre_ff, h1, y);
  cvt_w<<<4096, 256, 0, stream>>>(Wgate, wbuf, INTERD * HID);
  gemm8p<EPI_BF16><<<(INTERD / 256) * 16, 512, 0, stream>>>(
      y, wbuf, gate, nullptr, INTERD, HID);
  cvt_w<<<4096, 256, 0, stream>>>(Wup, wbuf, INTERD * HID);
  gemm8p<EPI_GELUMUL><<<(INTERD / 256) * 16, 512, 0, stream>>>(
      y, wbuf, gate, gate, INTERD, HID);
  cvt_w<<<4096, 256, 0, stream>>>(Wdown, wbuf, HID * INTERD);
  gemm8p<EPI_F32><<<(HID / 256) * 16, 512, 0, stream>>>(
      gate, wbuf, mlp, nullptr, HID, INTERD);

  fuse_out<<<MTOK, 256, 0, stream>>>(h1, mlp, w_post_ff, out);
}